// Round 3
// baseline (177.243 us; speedup 1.0000x reference)
//
#include <hip/hip_runtime.h>

// BahdanauAttention_16518444220431 — diagonal-DP recurrence on MI355X (gfx950).
// R13 = R11 + register-NEUTRAL dual-zk self-ks. R12 lesson: R11 sat at ~247/256
// regs at peak (pack zone); dual-zk(+32) + 6-slot afs all-live(+32) spilled
// (FETCH 52MB, chain 118us). Fix: NC 14->10 frees exactly 32 for the second zk;
// afs streamed in 3 tight 2-slot batches (A@top->ks10,11; B@after-self->12,13;
// C@after-ks11->14,15; max 2 batches live = 32). Self-ks: wave's packed zk is
// bit-identical to B-frags for ks in [4w,4w+4) (verified on HW in R12 — passed,
// only perf broke), so 16 of 68 MFMAs/interval run LDS-free, front-loaded to
// cover the post-barrier write+read warmup; LDS reads 32->24/wave/interval.
// zk lifetime: pack(h) -> LDS-write(top h+1) -> self-consume(top h+2); both
// phases' zk (zkU/zkD) live concurrently -> the +32 that must be paid by NC.
// All reg indices compile-time (explicit GSTEP/SELFSTEP instantiation).
// REGISTER LEDGER peak (mid-GEMM): w2c 80 + w1x 8 + acc 64 + zk-other 32 +
// afs<=32 + temps ~15 = ~231 < 256. Pack zone: 80+8+32+32+64+16 = 232 = R11.
// LESSONS: launch_bounds (256,2); FETCH>10MB = spill tripwire (R12);
// conflicts+setprio not the wall (R11); 128-AGPR acc spills (R9).

typedef __bf16 bf16x8 __attribute__((ext_vector_type(8)));
typedef __bf16 bf16x4 __attribute__((ext_vector_type(4)));
typedef float f32x16 __attribute__((ext_vector_type(16)));
typedef unsigned int uint2v __attribute__((ext_vector_type(2)));

#define MFMA32(a, b, c) __builtin_amdgcn_mfma_f32_32x32x16_bf16(a, b, c, 0, 0, 0)

__device__ __forceinline__ unsigned short f2bf(float f) {
  unsigned int u = __builtin_bit_cast(unsigned int, f);
  u += 0x7fffu + ((u >> 16) & 1u);
  return (unsigned short)(u >> 16);
}

// ws layout (bf16 elements):
//   [0,65536)        W2 fragments: ((ot*16+ks)*64+lane)*8+j ; o=ot*32+(lane&31), k=ks*16+(lane>>5)*8+j
//   [65536,131072)   W4 fragments, same permutation
//   [131072,135168)  W1-extra frags: lanes<32: j<4 -> W1[o][j], j==4 -> b1[o]+b2[o], else 0
//   [135168,139264)  W3-extra frags: j==4 -> b3[o]+2*b4[o]
__global__ void prep_kernel(const float* __restrict__ W1, const float* __restrict__ b1,
                            const float* __restrict__ W2, const float* __restrict__ b2,
                            const float* __restrict__ W3, const float* __restrict__ b3,
                            const float* __restrict__ W4, const float* __restrict__ b4,
                            unsigned short* __restrict__ ws) {
  int idx = blockIdx.x * 256 + threadIdx.x;
  if (idx >= 139264) return;
  float v = 0.0f;
  if (idx < 131072) {
    const float* W = (idx < 65536) ? W2 : W4;
    int i = idx & 65535;
    int j = i & 7, f = i >> 3;
    int lane = f & 63, slot = f >> 6;
    int ks = slot & 15, ot = slot >> 4;
    int o = ot * 32 + (lane & 31);
    int k = ks * 16 + (lane >> 5) * 8 + j;
    v = W[o * 256 + k];
  } else {
    int i = idx - 131072;
    bool first = (i < 4096);
    int ii = i & 4095;
    int j = ii & 7, f = ii >> 3;
    int lane = f & 63, ot = f >> 6;
    int o = ot * 32 + (lane & 31);
    if (lane < 32) {
      if (j < 4) v = first ? W1[o * 4 + j] : W3[o * 4 + j];
      else if (j == 4) v = first ? (b1[o] + b2[o]) : (b3[o] + 2.0f * b4[o]);
    }
  }
  ws[idx] = f2bf(v);
}

#define NC 10  // W2 slots cached in regs (0..3 = self ks); 10..15 streamed

// Load 2 afs slots (physical ks rotated by 4w) into AF[0..1][ot].
#define LOAD_AF(AF, S0) { \
    int ka_ = (4 * w + NC + (S0)) & 15; \
    AF[0][0] = __builtin_bit_cast(bf16x8, w2f[(ot0 * 16 + ka_) * 64 + l]); \
    AF[0][1] = __builtin_bit_cast(bf16x8, w2f[((ot0 + 1) * 16 + ka_) * 64 + l]); \
    int kb_ = (4 * w + NC + (S0) + 1) & 15; \
    AF[1][0] = __builtin_bit_cast(bf16x8, w2f[(ot0 * 16 + kb_) * 64 + l]); \
    AF[1][1] = __builtin_bit_cast(bf16x8, w2f[((ot0 + 1) * 16 + kb_) * 64 + l]); }

// One LDS-sourced K-slice MFMA cluster. KSR is a runtime scalar (address only).
#define GSTEP(UR, KSR, A0, A1) { \
    int c0_ = 2 * (KSR) + khalf; \
    bf16x8 bu0_ = __builtin_bit_cast(bf16x8, (UR)[c0_ * 64 + mrow0]); \
    bf16x8 bu1_ = __builtin_bit_cast(bf16x8, (UR)[c0_ * 64 + mrow1]); \
    acc[0][0] = MFMA32(A0, bu0_, acc[0][0]); \
    acc[0][1] = MFMA32(A1, bu0_, acc[0][1]); \
    acc[1][0] = MFMA32(A0, bu1_, acc[1][0]); \
    acc[1][1] = MFMA32(A1, bu1_, acc[1][1]); }

// Self K-slice from registers (zero LDS dependency). S is a literal 0..3.
#define SELFSTEP(ZS, S) { \
    bf16x8 bu0_ = __builtin_bit_cast(bf16x8, ZS[0][(S) >> 1][(S) & 1]); \
    bf16x8 bu1_ = __builtin_bit_cast(bf16x8, ZS[1][(S) >> 1][(S) & 1]); \
    acc[0][0] = MFMA32(w2c[0][S], bu0_, acc[0][0]); \
    acc[0][1] = MFMA32(w2c[1][S], bu0_, acc[0][1]); \
    acc[1][0] = MFMA32(w2c[0][S], bu1_, acc[1][0]); \
    acc[1][1] = MFMA32(w2c[1][S], bu1_, acc[1][1]); }

#define WRITEU(BUF, Z) { \
    int4* Uw_ = U[BUF]; \
    _Pragma("unroll") for (int mt = 0; mt < 2; ++mt) \
    _Pragma("unroll") for (int t2 = 0; t2 < 2; ++t2) \
    _Pragma("unroll") for (int p = 0; p < 2; ++p) \
      Uw_[((ot0 + t2) * 4 + 2 * p + khalf) * 64 + mt * 32 + lane31] = Z[mt][t2][p]; }

#define PACK(ZS) \
  _Pragma("unroll") for (int mt = 0; mt < 2; ++mt) { \
    _Pragma("unroll") for (int t2 = 0; t2 < 2; ++t2) { \
      unsigned lo[4], hi[4]; \
      _Pragma("unroll") for (int q = 0; q < 4; ++q) { \
        bf16x4 h; \
        h.x = (__bf16)fmaxf(acc[mt][t2][4 * q + 0], 0.0f); \
        h.y = (__bf16)fmaxf(acc[mt][t2][4 * q + 1], 0.0f); \
        h.z = (__bf16)fmaxf(acc[mt][t2][4 * q + 2], 0.0f); \
        h.w = (__bf16)fmaxf(acc[mt][t2][4 * q + 3], 0.0f); \
        uint2 u = __builtin_bit_cast(uint2, h); \
        lo[q] = u.x; hi[q] = u.y; \
      } \
      uint2v r0 = __builtin_amdgcn_permlane32_swap(lo[0], lo[1], false, false); \
      uint2v r1 = __builtin_amdgcn_permlane32_swap(hi[0], hi[1], false, false); \
      ZS[mt][t2][0] = make_int4((int)r0.x, (int)r1.x, (int)r0.y, (int)r1.y); \
      uint2v r2 = __builtin_amdgcn_permlane32_swap(lo[2], lo[3], false, false); \
      uint2v r3 = __builtin_amdgcn_permlane32_swap(hi[2], hi[3], false, false); \
      ZS[mt][t2][1] = make_int4((int)r2.x, (int)r3.x, (int)r2.y, (int)r3.y); \
    } \
  }

// One DP interval at compile-time phase PH, DP step T.
// ZS = this phase's zk (self B-frags = state T-1; repacked with state T at end).
// ZO = other phase's zk (LDS-written at top; its regs stay live for its own
// self-consume next interval).
#define INTERVAL(PH, T, ZS, ZO, DOW, DOG) { \
  bf16x8 afA[2][2], afB[2][2], afC[2][2]; \
  if (DOG) LOAD_AF(afA, 0) \
  if (DOW) WRITEU((PH) ^ 1, ZO) \
  f32x16 acc[2][2] = {}; \
  __builtin_amdgcn_s_setprio(1); \
  _Pragma("unroll") for (int mt = 0; mt < 2; ++mt) { \
    int m = mt ? mrow1 : mrow0; \
    int widx = (PH) == 0 ? (m + (T) - 1) : (m + 17 - (T)); \
    const int4* p = (l < 32) ? (xw + widx) : (&zc); \
    bf16x8 bx = __builtin_bit_cast(bf16x8, *p); \
    acc[mt][0] = MFMA32(w1x[0], bx, acc[mt][0]); \
    acc[mt][1] = MFMA32(w1x[1], bx, acc[mt][1]); \
  } \
  if (DOG) { \
    SELFSTEP(ZS, 0) SELFSTEP(ZS, 1) SELFSTEP(ZS, 2) SELFSTEP(ZS, 3) \
    LOAD_AF(afB, 2) \
    const int4* Ur = U[PH]; \
    GSTEP(Ur, (4 * w + 4) & 15, w2c[0][4], w2c[1][4]) \
    GSTEP(Ur, (4 * w + 5) & 15, w2c[0][5], w2c[1][5]) \
    GSTEP(Ur, (4 * w + 6) & 15, w2c[0][6], w2c[1][6]) \
    GSTEP(Ur, (4 * w + 7) & 15, w2c[0][7], w2c[1][7]) \
    GSTEP(Ur, (4 * w + 8) & 15, w2c[0][8], w2c[1][8]) \
    GSTEP(Ur, (4 * w + 9) & 15, w2c[0][9], w2c[1][9]) \
    GSTEP(Ur, (4 * w + 10) & 15, afA[0][0], afA[0][1]) \
    GSTEP(Ur, (4 * w + 11) & 15, afA[1][0], afA[1][1]) \
    LOAD_AF(afC, 4) \
    GSTEP(Ur, (4 * w + 12) & 15, afB[0][0], afB[0][1]) \
    GSTEP(Ur, (4 * w + 13) & 15, afB[1][0], afB[1][1]) \
    GSTEP(Ur, (4 * w + 14) & 15, afC[0][0], afC[0][1]) \
    GSTEP(Ur, (4 * w + 15) & 15, afC[1][0], afC[1][1]) \
  } \
  __builtin_amdgcn_s_setprio(0); \
  PACK(ZS) \
  __syncthreads(); \
}

// Final-GEMM phase: self slots 0..3 from ZS regs, rest from LDS, A from w4f.
#define FINAL_PH(PH, ZS) { \
  const int4* Sp = U[PH]; \
  _Pragma("unroll") for (int s = 0; s < 4; ++s) { \
    int ksr = 4 * w + s; \
    bf16x8 af0 = __builtin_bit_cast(bf16x8, w4f[(ot0 * 16 + ksr) * 64 + l]); \
    bf16x8 af1 = __builtin_bit_cast(bf16x8, w4f[((ot0 + 1) * 16 + ksr) * 64 + l]); \
    bf16x8 bu0 = __builtin_bit_cast(bf16x8, ZS[0][s >> 1][s & 1]); \
    bf16x8 bu1 = __builtin_bit_cast(bf16x8, ZS[1][s >> 1][s & 1]); \
    acc[0][0] = MFMA32(af0, bu0, acc[0][0]); \
    acc[0][1] = MFMA32(af1, bu0, acc[0][1]); \
    acc[1][0] = MFMA32(af0, bu1, acc[1][0]); \
    acc[1][1] = MFMA32(af1, bu1, acc[1][1]); \
  } \
  _Pragma("unroll") for (int i = 4; i < 16; ++i) { \
    int ksr = (4 * w + i) & 15; \
    int c0 = 2 * ksr + khalf; \
    bf16x8 bu0 = __builtin_bit_cast(bf16x8, Sp[c0 * 64 + mrow0]); \
    bf16x8 bu1 = __builtin_bit_cast(bf16x8, Sp[c0 * 64 + mrow1]); \
    bf16x8 af0 = __builtin_bit_cast(bf16x8, w4f[(ot0 * 16 + ksr) * 64 + l]); \
    bf16x8 af1 = __builtin_bit_cast(bf16x8, w4f[((ot0 + 1) * 16 + ksr) * 64 + l]); \
    acc[0][0] = MFMA32(af0, bu0, acc[0][0]); \
    acc[0][1] = MFMA32(af1, bu0, acc[0][1]); \
    acc[1][0] = MFMA32(af0, bu1, acc[1][0]); \
    acc[1][1] = MFMA32(af1, bu1, acc[1][1]); \
  } }

__global__ __launch_bounds__(256, 2)
void chain_kernel(const float* __restrict__ x, const unsigned short* __restrict__ ws,
                  float* __restrict__ out) {
  // U[ph], chunk-major: U[ph][c*64 + r] = bf16 elems [8c..8c+7] of row r.
  __shared__ int4 U[2][32 * 64];
  __shared__ int4 xw[80];   // [x0,x1,x2,x3,1,0,0,0] bf16 chunks, rows j0-8 .. j0+71
  __shared__ int4 zc;

  const int tid = threadIdx.x;
  const int l = tid & 63;
  const int w = tid >> 6;
  const int lane31 = l & 31;
  const int khalf = l >> 5;
  const int tile = blockIdx.x;
  const int b = tile >> 5;
  const int j0 = (tile & 31) * 64;

  const int4* w2f = (const int4*)ws;
  const int4* w4f = (const int4*)(ws + 65536);
  const int4* w1xg = (const int4*)(ws + 131072);
  const int4* w3xg = (const int4*)(ws + 135168);

  if (tid == 0) zc = make_int4(0, 0, 0, 0);
  if (tid < 80) {
    int j = j0 - 8 + tid;
    int4 c = make_int4(0, 0, 0, 0);
    if (j >= 0 && j < 2048) {
      const float* xb = x + (b * 4) * 2048 + j;
      unsigned short h0 = f2bf(xb[0]);
      unsigned short h1 = f2bf(xb[2048]);
      unsigned short h2 = f2bf(xb[4096]);
      unsigned short h3 = f2bf(xb[6144]);
      c = make_int4((int)(h0 | ((unsigned int)h1 << 16)),
                    (int)(h2 | ((unsigned int)h3 << 16)),
                    0x00003f80, 0);  // chunk[4] = bf16(1.0) multiplies the bias row
    }
    xw[tid] = c;
  }

  const int ot0 = w * 2;
  // Rotated W2 cache: slot i holds physical ks = (4w+i)&15, so slots 0..3 are
  // this wave's SELF ks (matching its own zk chunks) at compile-time indices.
  bf16x8 w2c[2][NC];
  bf16x8 w1x[2];
#pragma unroll
  for (int t2 = 0; t2 < 2; ++t2) {
    w1x[t2] = __builtin_bit_cast(bf16x8, w1xg[(ot0 + t2) * 64 + l]);
#pragma unroll
    for (int i = 0; i < NC; ++i) {
      int ksr = (4 * w + i) & 15;
      w2c[t2][i] = __builtin_bit_cast(bf16x8, w2f[((ot0 + t2) * 16 + ksr) * 64 + l]);
    }
  }
  __syncthreads();

  const int mrow0 = lane31;
  const int mrow1 = 32 + lane31;

  // zkU/zkD: packed state per phase, in B-fragment layout. zk[mt][t2][p] =
  // U chunk (ot0+t2)*4+2p+khalf at row mt*32+lane31. Lives 2 intervals:
  // packed at h, LDS-written at h+1 top, self-consumed (regs) at h+2 top.
  int4 zkU[2][2][2], zkD[2][2][2];

  // ---- t=1 peel (no previous state, no GEMM) ----
  INTERVAL(0, 1, zkU, zkD, false, false)
  INTERVAL(1, 1, zkD, zkU, true, false)

#pragma unroll 1
  for (int tt = 1; tt < 8; ++tt) {
    INTERVAL(0, tt + 1, zkU, zkD, true, true)
    INTERVAL(1, tt + 1, zkD, zkU, true, true)
  }

  // ---- flush last down-state (zkD = state h=15) -> U1, then final GEMM ----
  WRITEU(1, zkD)
  __syncthreads();

  // ---- final: miu^T = relu(W3x + b3 + 2b4 + W4*U0 + W4*U1), in-block ----
  {
    f32x16 acc[2][2] = {};   // [mt][ot]
    bf16x8 w3x0 = __builtin_bit_cast(bf16x8, w3xg[ot0 * 64 + l]);
    bf16x8 w3x1 = __builtin_bit_cast(bf16x8, w3xg[(ot0 + 1) * 64 + l]);
    __builtin_amdgcn_s_setprio(1);
#pragma unroll
    for (int mt = 0; mt < 2; ++mt) {
      int m = mt ? mrow1 : mrow0;
      const int4* p = (l < 32) ? (xw + m + 8) : (&zc);
      bf16x8 bx = __builtin_bit_cast(bf16x8, *p);
      acc[mt][0] = MFMA32(w3x0, bx, acc[mt][0]);
      acc[mt][1] = MFMA32(w3x1, bx, acc[mt][1]);
    }
    FINAL_PH(0, zkU)
    FINAL_PH(1, zkD)
    __builtin_amdgcn_s_setprio(0);
#pragma unroll
    for (int mt = 0; mt < 2; ++mt) {
      int m = mt ? mrow1 : mrow0;
      int pbase = (b * 2048 + j0 + m) * 256;
#pragma unroll
      for (int t2 = 0; t2 < 2; ++t2) {
#pragma unroll
        for (int q = 0; q < 4; ++q) {
          int ob = (ot0 + t2) * 32 + 8 * q + 4 * khalf;
          float4 v;
          v.x = fmaxf(acc[mt][t2][4 * q + 0], 0.0f);
          v.y = fmaxf(acc[mt][t2][4 * q + 1], 0.0f);
          v.z = fmaxf(acc[mt][t2][4 * q + 2], 0.0f);
          v.w = fmaxf(acc[mt][t2][4 * q + 3], 0.0f);
          *(float4*)(out + pbase + ob) = v;
        }
      }
    }
  }
}

extern "C" void kernel_launch(void* const* d_in, const int* in_sizes, int n_in,
                              void* d_out, int out_size, void* d_ws, size_t ws_size,
                              hipStream_t stream) {
  const float* x  = (const float*)d_in[0];
  const float* W1 = (const float*)d_in[1];
  const float* b1 = (const float*)d_in[2];
  const float* W2 = (const float*)d_in[3];
  const float* b2 = (const float*)d_in[4];
  const float* W3 = (const float*)d_in[5];
  const float* b3 = (const float*)d_in[6];
  const float* W4 = (const float*)d_in[7];
  const float* b4 = (const float*)d_in[8];
  unsigned short* ws = (unsigned short*)d_ws;

  prep_kernel<<<544, 256, 0, stream>>>(W1, b1, W2, b2, W3, b3, W4, b4, ws);
  chain_kernel<<<512, 256, 0, stream>>>(x, ws, (float*)d_out);
}

// Round 4
// 134.723 us; speedup vs baseline: 1.3156x; 1.3156x over previous
//
#include <hip/hip_runtime.h>

// BahdanauAttention_16518444220431 — diagonal-DP recurrence on MI355X (gfx950).
// R14 = R11 reverted (dual-zk abandoned: R12+R13 both spilled at VGPR 128,
// FETCH 52MB — the +64-reg cross-interval state is unaffordable) with the
// SYNC STRUCTURE attacked instead: 32-row tiles (1024 blocks), 4 LDS state
// buffers (UA[2]/UB[2], 16KB each), writes at interval END -> all hazards
// covered by ONE barrier per up+down pair (9/block vs 18). No barrier between
// up and down steps: down's 16 ds_reads (data 2 intervals old) can hoist into
// up's MFMA chain — ~70-MFMA straight-line regions. mt gone: acc 32 AGPR,
// zk 16; NC=16 (all W2 cached, afs streaming deleted). LEDGER: w2c 128 +
// w1x 8 + acc 32 + zk 16 + temps ~20 = 204 < 256. Theory: R11's pipes sum
// to the wall (MFMA 4.4k + LDS 3.9k + VALU 2k ~= 9.25k/interval) = zero
// overlap; barriers fence the scheduler every 35 MFMAs. LESSONS: launch
// bounds (256,2); FETCH>10MB = spill tripwire (R12/R13); conflicts+setprio
// not the wall (R11); cross-interval reg state spills (R12/R13).

typedef __bf16 bf16x8 __attribute__((ext_vector_type(8)));
typedef __bf16 bf16x4 __attribute__((ext_vector_type(4)));
typedef float f32x16 __attribute__((ext_vector_type(16)));
typedef unsigned int uint2v __attribute__((ext_vector_type(2)));

#define MFMA32(a, b, c) __builtin_amdgcn_mfma_f32_32x32x16_bf16(a, b, c, 0, 0, 0)

__device__ __forceinline__ unsigned short f2bf(float f) {
  unsigned int u = __builtin_bit_cast(unsigned int, f);
  u += 0x7fffu + ((u >> 16) & 1u);
  return (unsigned short)(u >> 16);
}

// ws layout (bf16 elements):
//   [0,65536)        W2 fragments: ((ot*16+ks)*64+lane)*8+j ; o=ot*32+(lane&31), k=ks*16+(lane>>5)*8+j
//   [65536,131072)   W4 fragments, same permutation
//   [131072,135168)  W1-extra frags: lanes<32: j<4 -> W1[o][j], j==4 -> b1[o]+b2[o], else 0
//   [135168,139264)  W3-extra frags: j==4 -> b3[o]+2*b4[o]
__global__ void prep_kernel(const float* __restrict__ W1, const float* __restrict__ b1,
                            const float* __restrict__ W2, const float* __restrict__ b2,
                            const float* __restrict__ W3, const float* __restrict__ b3,
                            const float* __restrict__ W4, const float* __restrict__ b4,
                            unsigned short* __restrict__ ws) {
  int idx = blockIdx.x * 256 + threadIdx.x;
  if (idx >= 139264) return;
  float v = 0.0f;
  if (idx < 131072) {
    const float* W = (idx < 65536) ? W2 : W4;
    int i = idx & 65535;
    int j = i & 7, f = i >> 3;
    int lane = f & 63, slot = f >> 6;
    int ks = slot & 15, ot = slot >> 4;
    int o = ot * 32 + (lane & 31);
    int k = ks * 16 + (lane >> 5) * 8 + j;
    v = W[o * 256 + k];
  } else {
    int i = idx - 131072;
    bool first = (i < 4096);
    int ii = i & 4095;
    int j = ii & 7, f = ii >> 3;
    int lane = f & 63, ot = f >> 6;
    int o = ot * 32 + (lane & 31);
    if (lane < 32) {
      if (j < 4) v = first ? W1[o * 4 + j] : W3[o * 4 + j];
      else if (j == 4) v = first ? (b1[o] + b2[o]) : (b3[o] + 2.0f * b4[o]);
    }
  }
  ws[idx] = f2bf(v);
}

// One K=16 slice of the state GEMM: 1 ds_read_b128 feeds 2 MFMAs.
#define GSTEP(RB, KS) { \
    bf16x8 bu_ = __builtin_bit_cast(bf16x8, (RB)[(2 * (KS) + khalf) * 32 + lane31]); \
    acc[0] = MFMA32(w2c[0][KS], bu_, acc[0]); \
    acc[1] = MFMA32(w2c[1][KS], bu_, acc[1]); }

// relu + bf16 pack + permlane32_swap into full-int4 chunks, write to WB.
// Chunk (ot0+t2)*4 + 2p + khalf, row lane31; contiguous 512B runs, conflict-free.
#define PACKWRITE(WB) { \
    _Pragma("unroll") for (int t2 = 0; t2 < 2; ++t2) { \
      unsigned lo[4], hi[4]; \
      _Pragma("unroll") for (int q = 0; q < 4; ++q) { \
        bf16x4 h; \
        h.x = (__bf16)fmaxf(acc[t2][4 * q + 0], 0.0f); \
        h.y = (__bf16)fmaxf(acc[t2][4 * q + 1], 0.0f); \
        h.z = (__bf16)fmaxf(acc[t2][4 * q + 2], 0.0f); \
        h.w = (__bf16)fmaxf(acc[t2][4 * q + 3], 0.0f); \
        uint2 u = __builtin_bit_cast(uint2, h); \
        lo[q] = u.x; hi[q] = u.y; \
      } \
      uint2v r0 = __builtin_amdgcn_permlane32_swap(lo[0], lo[1], false, false); \
      uint2v r1 = __builtin_amdgcn_permlane32_swap(hi[0], hi[1], false, false); \
      (WB)[((ot0 + t2) * 4 + khalf) * 32 + lane31] = \
          make_int4((int)r0.x, (int)r1.x, (int)r0.y, (int)r1.y); \
      uint2v r2 = __builtin_amdgcn_permlane32_swap(lo[2], lo[3], false, false); \
      uint2v r3 = __builtin_amdgcn_permlane32_swap(hi[2], hi[3], false, false); \
      (WB)[((ot0 + t2) * 4 + 2 + khalf) * 32 + lane31] = \
          make_int4((int)r2.x, (int)r3.x, (int)r2.y, (int)r3.y); \
    } }

// One DP step at phase PH (compile-time), step T. Reads RB (state T-1,
// written 2 intervals ago), writes state T to WB at the END (pre-barrier).
#define INTERVAL(PH, T, RB, WB, DOG) { \
  f32x16 acc[2] = {}; \
  { int widx = (PH) == 0 ? (lane31 + (T) - 1) : (lane31 + 17 - (T)); \
    const int4* p_ = (l < 32) ? (xw + widx) : (&zc); \
    bf16x8 bx_ = __builtin_bit_cast(bf16x8, *p_); \
    acc[0] = MFMA32(w1x[0], bx_, acc[0]); \
    acc[1] = MFMA32(w1x[1], bx_, acc[1]); } \
  if (DOG) { \
    __builtin_amdgcn_s_setprio(1); \
    GSTEP(RB, 0)  GSTEP(RB, 1)  GSTEP(RB, 2)  GSTEP(RB, 3) \
    GSTEP(RB, 4)  GSTEP(RB, 5)  GSTEP(RB, 6)  GSTEP(RB, 7) \
    GSTEP(RB, 8)  GSTEP(RB, 9)  GSTEP(RB, 10) GSTEP(RB, 11) \
    GSTEP(RB, 12) GSTEP(RB, 13) GSTEP(RB, 14) GSTEP(RB, 15) \
    __builtin_amdgcn_s_setprio(0); \
  } \
  PACKWRITE(WB) }

__global__ __launch_bounds__(256, 2)
void chain_kernel(const float* __restrict__ x, const unsigned short* __restrict__ ws,
                  float* __restrict__ out) {
  // Per-phase double-buffered state, chunk-major: buf[c*32 + r] = bf16 elems
  // [8c..8c+7] of state row r (32 rows per tile). 4 x 16KB = 64KB.
  __shared__ int4 UA[2][1024];
  __shared__ int4 UB[2][1024];
  __shared__ int4 xw[48];   // [x0,x1,x2,x3,1,0,0,0] bf16 chunks, rows j0-8 .. j0+39
  __shared__ int4 zc;

  const int tid = threadIdx.x;
  const int l = tid & 63;
  const int w = tid >> 6;
  const int lane31 = l & 31;
  const int khalf = l >> 5;
  const int tile = blockIdx.x;
  const int b = tile >> 6;
  const int j0 = (tile & 63) * 32;

  const int4* w2f = (const int4*)ws;
  const int4* w4f = (const int4*)(ws + 65536);
  const int4* w1xg = (const int4*)(ws + 131072);
  const int4* w3xg = (const int4*)(ws + 135168);

  if (tid == 0) zc = make_int4(0, 0, 0, 0);
  if (tid < 48) {
    int j = j0 - 8 + tid;
    int4 c = make_int4(0, 0, 0, 0);
    if (j >= 0 && j < 2048) {
      const float* xb = x + (b * 4) * 2048 + j;
      unsigned short h0 = f2bf(xb[0]);
      unsigned short h1 = f2bf(xb[2048]);
      unsigned short h2 = f2bf(xb[4096]);
      unsigned short h3 = f2bf(xb[6144]);
      c = make_int4((int)(h0 | ((unsigned int)h1 << 16)),
                    (int)(h2 | ((unsigned int)h3 << 16)),
                    0x00003f80, 0);  // chunk[4] = bf16(1.0) multiplies the bias row
    }
    xw[tid] = c;
  }

  const int ot0 = w * 2;
  bf16x8 w2c[2][16];   // ALL 16 ks cached (no streaming)
  bf16x8 w1x[2];
#pragma unroll
  for (int t2 = 0; t2 < 2; ++t2) {
    w1x[t2] = __builtin_bit_cast(bf16x8, w1xg[(ot0 + t2) * 64 + l]);
#pragma unroll
    for (int i = 0; i < 16; ++i)
      w2c[t2][i] = __builtin_bit_cast(bf16x8, w2f[((ot0 + t2) * 16 + i) * 64 + l]);
  }
  __syncthreads();

  // ---- t=1 peel (no previous state, no GEMM) ----
  INTERVAL(0, 1, UA[0], UA[0], false)
  INTERVAL(1, 1, UB[0], UB[0], false)
  __syncthreads();

  // ---- t=2..8: one barrier per up+down pair ----
#pragma unroll 1
  for (int k = 1; k < 8; ++k) {
    const int4* ra = UA[(k - 1) & 1];
    int4* wa = UA[k & 1];
    const int4* rb = UB[(k - 1) & 1];
    int4* wb = UB[k & 1];
    const int T = k + 1;
    INTERVAL(0, T, ra, wa, true)
    INTERVAL(1, T, rb, wb, true)
    __syncthreads();
  }

  // ---- final: miu^T = relu(W3x + b3 + 2b4 + W4*up(8) + W4*down(8)) ----
  // up(8) is in UA[1], down(8) in UB[1] (k=7 wrote buf 1; barrier above).
  {
    f32x16 acc[2] = {};
    { int widx = lane31 + 8;
      const int4* p_ = (l < 32) ? (xw + widx) : (&zc);
      bf16x8 bx = __builtin_bit_cast(bf16x8, *p_);
      bf16x8 w3x0 = __builtin_bit_cast(bf16x8, w3xg[ot0 * 64 + l]);
      bf16x8 w3x1 = __builtin_bit_cast(bf16x8, w3xg[(ot0 + 1) * 64 + l]);
      acc[0] = MFMA32(w3x0, bx, acc[0]);
      acc[1] = MFMA32(w3x1, bx, acc[1]); }
    __builtin_amdgcn_s_setprio(1);
#pragma unroll 1
    for (int ph = 0; ph < 2; ++ph) {
      const int4* Sp = ph ? UB[1] : UA[1];
#pragma unroll
      for (int ks = 0; ks < 16; ++ks) {
        bf16x8 af0 = __builtin_bit_cast(bf16x8, w4f[(ot0 * 16 + ks) * 64 + l]);
        bf16x8 af1 = __builtin_bit_cast(bf16x8, w4f[((ot0 + 1) * 16 + ks) * 64 + l]);
        bf16x8 bu = __builtin_bit_cast(bf16x8, Sp[(2 * ks + khalf) * 32 + lane31]);
        acc[0] = MFMA32(af0, bu, acc[0]);
        acc[1] = MFMA32(af1, bu, acc[1]);
      }
    }
    __builtin_amdgcn_s_setprio(0);
    int pbase = (b * 2048 + j0 + lane31) * 256;
#pragma unroll
    for (int t2 = 0; t2 < 2; ++t2) {
#pragma unroll
      for (int q = 0; q < 4; ++q) {
        int ob = (ot0 + t2) * 32 + 8 * q + 4 * khalf;
        float4 v;
        v.x = fmaxf(acc[t2][4 * q + 0], 0.0f);
        v.y = fmaxf(acc[t2][4 * q + 1], 0.0f);
        v.z = fmaxf(acc[t2][4 * q + 2], 0.0f);
        v.w = fmaxf(acc[t2][4 * q + 3], 0.0f);
        *(float4*)(out + pbase + ob) = v;
      }
    }
  }
}

extern "C" void kernel_launch(void* const* d_in, const int* in_sizes, int n_in,
                              void* d_out, int out_size, void* d_ws, size_t ws_size,
                              hipStream_t stream) {
  const float* x  = (const float*)d_in[0];
  const float* W1 = (const float*)d_in[1];
  const float* b1 = (const float*)d_in[2];
  const float* W2 = (const float*)d_in[3];
  const float* b2 = (const float*)d_in[4];
  const float* W3 = (const float*)d_in[5];
  const float* b3 = (const float*)d_in[6];
  const float* W4 = (const float*)d_in[7];
  const float* b4 = (const float*)d_in[8];
  unsigned short* ws = (unsigned short*)d_ws;

  prep_kernel<<<544, 256, 0, stream>>>(W1, b1, W2, b2, W3, b3, W4, b4, ws);
  chain_kernel<<<1024, 256, 0, stream>>>(x, ws, (float*)d_out);
}

// Round 6
// 131.593 us; speedup vs baseline: 1.3469x; 1.0238x over previous
//
#include <hip/hip_runtime.h>

// BahdanauAttention_16518444220431 — diagonal-DP recurrence on MI355X (gfx950).
// R16 = R11 EXACT (verified pass, chain 65.4us) + CO-RESIDENT BLOCK STAGGER.
// R15's fused-pair variant failed post-timing determinism (absmax 0.67 on a
// later replay) — scheduling-sensitive; abandoned. Back to the verified base,
// timing-only change: MfmaUtil pinned 45-48% across R10-R14 while per-SIMD
// MFMA-bound is 4386 cyc/interval vs 9250 measured. Each SIMD hosts 2 waves
// from the 2 co-resident blocks (independent barriers); at random phase
// expected util ~72%, measured 47% = single-stream density => blocks are
// PHASE-LOCKED (launched together, symmetric contention keeps them locked).
// Fix: blocks with bit8 set (co-resident pair = (i,i+256) under round-robin
// XCD dispatch: XCD=i%8, CU=(i/8)%32) sleep ~4.6k cyc (half interval) once
// at start. Falsified so far: LDS conflicts (R11), setprio (R11), barrier
// count (R14), cross-interval reg state (R12/R13 spill), fused pair (R15
// nondeterministic). LESSONS: launch_bounds (256,2); FETCH>10MB = spill.

typedef __bf16 bf16x8 __attribute__((ext_vector_type(8)));
typedef __bf16 bf16x4 __attribute__((ext_vector_type(4)));
typedef float f32x16 __attribute__((ext_vector_type(16)));
typedef unsigned int uint2v __attribute__((ext_vector_type(2)));

#define MFMA32(a, b, c) __builtin_amdgcn_mfma_f32_32x32x16_bf16(a, b, c, 0, 0, 0)

__device__ __forceinline__ unsigned short f2bf(float f) {
  unsigned int u = __builtin_bit_cast(unsigned int, f);
  u += 0x7fffu + ((u >> 16) & 1u);
  return (unsigned short)(u >> 16);
}

// ws layout (bf16 elements):
//   [0,65536)        W2 fragments: ((ot*16+ks)*64+lane)*8+j ; o=ot*32+(lane&31), k=ks*16+(lane>>5)*8+j
//   [65536,131072)   W4 fragments, same permutation
//   [131072,135168)  W1-extra frags: lanes<32: j<4 -> W1[o][j], j==4 -> b1[o]+b2[o], else 0
//   [135168,139264)  W3-extra frags: j==4 -> b3[o]+2*b4[o]
__global__ void prep_kernel(const float* __restrict__ W1, const float* __restrict__ b1,
                            const float* __restrict__ W2, const float* __restrict__ b2,
                            const float* __restrict__ W3, const float* __restrict__ b3,
                            const float* __restrict__ W4, const float* __restrict__ b4,
                            unsigned short* __restrict__ ws) {
  int idx = blockIdx.x * 256 + threadIdx.x;
  if (idx >= 139264) return;
  float v = 0.0f;
  if (idx < 131072) {
    const float* W = (idx < 65536) ? W2 : W4;
    int i = idx & 65535;
    int j = i & 7, f = i >> 3;
    int lane = f & 63, slot = f >> 6;
    int ks = slot & 15, ot = slot >> 4;
    int o = ot * 32 + (lane & 31);
    int k = ks * 16 + (lane >> 5) * 8 + j;
    v = W[o * 256 + k];
  } else {
    int i = idx - 131072;
    bool first = (i < 4096);
    int ii = i & 4095;
    int j = ii & 7, f = ii >> 3;
    int lane = f & 63, ot = f >> 6;
    int o = ot * 32 + (lane & 31);
    if (lane < 32) {
      if (j < 4) v = first ? W1[o * 4 + j] : W3[o * 4 + j];
      else if (j == 4) v = first ? (b1[o] + b2[o]) : (b3[o] + 2.0f * b4[o]);
    }
  }
  ws[idx] = f2bf(v);
}

#define NC 14  // W2 ks cached in regs; ks 14,15 loaded at interval top

__global__ __launch_bounds__(256, 2)
void chain_kernel(const float* __restrict__ x, const unsigned short* __restrict__ ws,
                  float* __restrict__ out) {
  // U[ph], chunk-major: U[ph][c*64 + r] = bf16 elems [8c..8c+7] of row r.
  __shared__ int4 U[2][32 * 64];
  __shared__ int4 xw[80];   // [x0,x1,x2,x3,1,0,0,0] bf16 chunks, rows j0-8 .. j0+71
  __shared__ int4 zc;

  const int tid = threadIdx.x;
  const int l = tid & 63;
  const int w = tid >> 6;
  const int lane31 = l & 31;
  const int khalf = l >> 5;
  const int tile = blockIdx.x;
  const int b = tile >> 5;
  const int j0 = (tile & 31) * 64;

  // R16: stagger the co-resident pair (i, i+256) by ~half an interval
  // (~4.6k cyc) so the two blocks' MFMA bursts interleave on each SIMD
  // instead of phase-locking. Timing-only; no semantic effect.
  if ((tile >> 8) & 1) __builtin_amdgcn_s_sleep(72);

  const int4* w2f = (const int4*)ws;
  const int4* w4f = (const int4*)(ws + 65536);
  const int4* w1xg = (const int4*)(ws + 131072);
  const int4* w3xg = (const int4*)(ws + 135168);

  if (tid == 0) zc = make_int4(0, 0, 0, 0);
  if (tid < 80) {
    int j = j0 - 8 + tid;
    int4 c = make_int4(0, 0, 0, 0);
    if (j >= 0 && j < 2048) {
      const float* xb = x + (b * 4) * 2048 + j;
      unsigned short h0 = f2bf(xb[0]);
      unsigned short h1 = f2bf(xb[2048]);
      unsigned short h2 = f2bf(xb[4096]);
      unsigned short h3 = f2bf(xb[6144]);
      c = make_int4((int)(h0 | ((unsigned int)h1 << 16)),
                    (int)(h2 | ((unsigned int)h3 << 16)),
                    0x00003f80, 0);  // chunk[4] = bf16(1.0) multiplies the bias row
    }
    xw[tid] = c;
  }

  const int ot0 = w * 2;
  bf16x8 w2c[2][NC];
  bf16x8 w1x[2];
#pragma unroll
  for (int t2 = 0; t2 < 2; ++t2) {
    w1x[t2] = __builtin_bit_cast(bf16x8, w1xg[(ot0 + t2) * 64 + l]);
#pragma unroll
    for (int ks = 0; ks < NC; ++ks)
      w2c[t2][ks] = __builtin_bit_cast(bf16x8, w2f[((ot0 + t2) * 16 + ks) * 64 + l]);
  }
  __syncthreads();

  const int mrow0 = lane31;
  const int mrow1 = 32 + lane31;

  // Swapped packed state: zk[mt][t2][p] = full U int4 for chunk (ot0+t2)*4+2p
  // (lanes<32) / +2p+1 (lanes>=32), row mt*32+lane31.  Built via permlane32_swap.
  int4 zk[2][2][2];

#pragma unroll 1
  for (int half = 0; half < 16; ++half) {   // half = 2*(t-1) + interval
    const int t = (half >> 1) + 1;
    const int ph = half & 1;                // GEMM phase this interval

    // ---- issue the 4 non-cached A loads FIRST (used ~500 cyc later) ----
    bf16x8 afs[2][2];
#pragma unroll
    for (int s = 0; s < 2; ++s) {
      afs[s][0] = __builtin_bit_cast(bf16x8, w2f[(ot0 * 16 + NC + s) * 64 + l]);
      afs[s][1] = __builtin_bit_cast(bf16x8, w2f[((ot0 + 1) * 16 + NC + s) * 64 + l]);
    }

    f32x16 acc[2][2] = {};                  // [mt][t2] — single phase live

    // ---- write PREVIOUS interval's swapped state: 8x ds_write_b128,
    //      contiguous 512B runs per store -> bank-conflict-free ----
    if (half > 0) {
      int4* Uw = U[ph ^ 1];
#pragma unroll
      for (int mt = 0; mt < 2; ++mt)
#pragma unroll
        for (int t2 = 0; t2 < 2; ++t2)
#pragma unroll
          for (int p = 0; p < 2; ++p)
            Uw[((ot0 + t2) * 4 + 2 * p + khalf) * 64 + mt * 32 + lane31] = zk[mt][t2][p];
    }

    __builtin_amdgcn_s_setprio(1);

    // ---- extra K=16 step: adds a[pos] + bias (zero chunk beyond seq edges) ----
#pragma unroll
    for (int mt = 0; mt < 2; ++mt) {
      int m = mt ? mrow1 : mrow0;
      int widx = (ph == 0) ? (m + t - 1) : (m + 17 - t);
      const int4* p = (l < 32) ? (xw + widx) : (&zc);
      bf16x8 bx = __builtin_bit_cast(bf16x8, *p);
      acc[mt][0] = MFMA32(w1x[0], bx, acc[mt][0]);
      acc[mt][1] = MFMA32(w1x[1], bx, acc[mt][1]);
    }

    // ---- main GEMM over this phase's previous state (skip at t==1) ----
    if (t > 1) {
      const int4* Ur = U[ph];
#pragma unroll
      for (int ks = 0; ks < 16; ++ks) {
        int c0 = 2 * ks + khalf;
        bf16x8 bu0 = __builtin_bit_cast(bf16x8, Ur[c0 * 64 + mrow0]);
        bf16x8 bu1 = __builtin_bit_cast(bf16x8, Ur[c0 * 64 + mrow1]);
        bf16x8 af0, af1;
        if (ks < NC) { af0 = w2c[0][ks]; af1 = w2c[1][ks]; }
        else         { af0 = afs[ks - NC][0]; af1 = afs[ks - NC][1]; }
        acc[0][0] = MFMA32(af0, bu0, acc[0][0]);
        acc[0][1] = MFMA32(af1, bu0, acc[0][1]);
        acc[1][0] = MFMA32(af0, bu1, acc[1][0]);
        acc[1][1] = MFMA32(af1, bu1, acc[1][1]);
      }
    }

    __builtin_amdgcn_s_setprio(0);

    // ---- relu + bf16 pack, then permlane32_swap into full-int4 form ----
#pragma unroll
    for (int mt = 0; mt < 2; ++mt) {
#pragma unroll
      for (int t2 = 0; t2 < 2; ++t2) {
        unsigned lo[4], hi[4];
#pragma unroll
        for (int q = 0; q < 4; ++q) {
          bf16x4 h;
          h.x = (__bf16)fmaxf(acc[mt][t2][4 * q + 0], 0.0f);
          h.y = (__bf16)fmaxf(acc[mt][t2][4 * q + 1], 0.0f);
          h.z = (__bf16)fmaxf(acc[mt][t2][4 * q + 2], 0.0f);
          h.w = (__bf16)fmaxf(acc[mt][t2][4 * q + 3], 0.0f);
          uint2 u = __builtin_bit_cast(uint2, h);
          lo[q] = u.x; hi[q] = u.y;
        }
        // pair (q0,q1)=(0,1): lanes<32 keep q0-lo halves, gain q0-hi halves
        // from lanes>=32; lanes>=32 end with the full q1 int4.
        uint2v r0 = __builtin_amdgcn_permlane32_swap(lo[0], lo[1], false, false);
        uint2v r1 = __builtin_amdgcn_permlane32_swap(hi[0], hi[1], false, false);
        zk[mt][t2][0] = make_int4((int)r0.x, (int)r1.x, (int)r0.y, (int)r1.y);
        uint2v r2 = __builtin_amdgcn_permlane32_swap(lo[2], lo[3], false, false);
        uint2v r3 = __builtin_amdgcn_permlane32_swap(hi[2], hi[3], false, false);
        zk[mt][t2][1] = make_int4((int)r2.x, (int)r3.x, (int)r2.y, (int)r3.y);
      }
    }
    __syncthreads();
  }

  // ---- flush last down-state (zk of half=15) -> U1, then final GEMM ----
  {
    int4* Uw = U[1];
#pragma unroll
    for (int mt = 0; mt < 2; ++mt) {
      int row = mt ? mrow1 : mrow0;
#pragma unroll
      for (int t2 = 0; t2 < 2; ++t2) {
#pragma unroll
        for (int p = 0; p < 2; ++p) {
          int idx = ((ot0 + t2) * 4 + 2 * p + khalf) * 64 + (mt ? mrow1 : mrow0);
          Uw[idx] = zk[mt][t2][p];
          (void)row;
        }
      }
    }
  }
  __syncthreads();

  // ---- final: miu^T = relu(W3x + b3 + 2b4 + W4*U0 + W4*U1), in-block ----
  {
    f32x16 acc[2][2] = {};   // [mt][ot]
    bf16x8 w3x0 = __builtin_bit_cast(bf16x8, w3xg[ot0 * 64 + l]);
    bf16x8 w3x1 = __builtin_bit_cast(bf16x8, w3xg[(ot0 + 1) * 64 + l]);
    __builtin_amdgcn_s_setprio(1);
#pragma unroll
    for (int mt = 0; mt < 2; ++mt) {
      int m = mt ? mrow1 : mrow0;
      const int4* p = (l < 32) ? (xw + m + 8) : (&zc);
      bf16x8 bx = __builtin_bit_cast(bf16x8, *p);
      acc[mt][0] = MFMA32(w3x0, bx, acc[mt][0]);
      acc[mt][1] = MFMA32(w3x1, bx, acc[mt][1]);
    }
#pragma unroll 1
    for (int ph = 0; ph < 2; ++ph) {
      const int4* Sp = U[ph];
#pragma unroll
      for (int ks = 0; ks < 16; ++ks) {
        int c0 = 2 * ks + khalf;
        bf16x8 bu0 = __builtin_bit_cast(bf16x8, Sp[c0 * 64 + mrow0]);
        bf16x8 bu1 = __builtin_bit_cast(bf16x8, Sp[c0 * 64 + mrow1]);
        bf16x8 af0 = __builtin_bit_cast(bf16x8, w4f[(ot0 * 16 + ks) * 64 + l]);
        bf16x8 af1 = __builtin_bit_cast(bf16x8, w4f[((ot0 + 1) * 16 + ks) * 64 + l]);
        acc[0][0] = MFMA32(af0, bu0, acc[0][0]);
        acc[0][1] = MFMA32(af1, bu0, acc[0][1]);
        acc[1][0] = MFMA32(af0, bu1, acc[1][0]);
        acc[1][1] = MFMA32(af1, bu1, acc[1][1]);
      }
    }
    __builtin_amdgcn_s_setprio(0);
#pragma unroll
    for (int mt = 0; mt < 2; ++mt) {
      int m = mt ? mrow1 : mrow0;
      int pbase = (b * 2048 + j0 + m) * 256;
#pragma unroll
      for (int t2 = 0; t2 < 2; ++t2) {
#pragma unroll
        for (int q = 0; q < 4; ++q) {
          int ob = (ot0 + t2) * 32 + 8 * q + 4 * khalf;
          float4 v;
          v.x = fmaxf(acc[mt][t2][4 * q + 0], 0.0f);
          v.y = fmaxf(acc[mt][t2][4 * q + 1], 0.0f);
          v.z = fmaxf(acc[mt][t2][4 * q + 2], 0.0f);
          v.w = fmaxf(acc[mt][t2][4 * q + 3], 0.0f);
          *(float4*)(out + pbase + ob) = v;
        }
      }
    }
  }
}

extern "C" void kernel_launch(void* const* d_in, const int* in_sizes, int n_in,
                              void* d_out, int out_size, void* d_ws, size_t ws_size,
                              hipStream_t stream) {
  const float* x  = (const float*)d_in[0];
  const float* W1 = (const float*)d_in[1];
  const float* b1 = (const float*)d_in[2];
  const float* W2 = (const float*)d_in[3];
  const float* b2 = (const float*)d_in[4];
  const float* W3 = (const float*)d_in[5];
  const float* b3 = (const float*)d_in[6];
  const float* W4 = (const float*)d_in[7];
  const float* b4 = (const float*)d_in[8];
  unsigned short* ws = (unsigned short*)d_ws;

  prep_kernel<<<544, 256, 0, stream>>>(W1, b1, W2, b2, W3, b3, W4, b4, ws);
  chain_kernel<<<512, 256, 0, stream>>>(x, ws, (float*)d_out);
}

// Round 7
// 129.533 us; speedup vs baseline: 1.3683x; 1.0159x over previous
//
#include <hip/hip_runtime.h>

// BahdanauAttention_16518444220431 — diagonal-DP recurrence on MI355X (gfx950).
// R17 = R14 (verified, 32-row tiles, pair structure, 1 barrier/pair) +
// REGISTER-FEASIBLE SELF-KS + VECTORIZED PREP.
// Self-ks: wave w's packed zk (4 int4/chain) is bit-identical to the B-frags
// for ks in [4w,4w+4) (proven correct in R12/R13 runs — both PASSED, only
// perf broke from spills). On the PAIR structure zk crosses ONE barrier
// (pack at pair k -> self-consume at pair k+1), not two -> 32 regs total,
// not 64. 4 of 16 ks per GEMM run LDS-free, front-loaded to cover the
// post-barrier LDS warmup; reads 32->24/wave/pair. ks-ROTATION (R13,
// proven): w2c slot i = physical ks (4w+i)&15, self slots 0..3 compile-time.
// LEDGER worst (down GEMM): w2c[2][10]=80 + afs 16 + w1x 8 + zk_old 16 +
// zk_new 16 + acc 32 + temps ~25 = 193 < 256.
// PREP vectorized: 8 elems/thread, float4 loads, int4 stores, 68 blocks —
// probes whether the ~66us gap between chain (65us) and total (131us) is
// prep cost or harness floor.
// Falsified: conflicts (R11), setprio (R11), barrier count (R14), 2-interval
// reg state (R12/R13 spill), fused write (R15 race), block stagger (R16).
// LESSONS: launch_bounds (256,2); FETCH>10MB = spill tripwire.

typedef __bf16 bf16x8 __attribute__((ext_vector_type(8)));
typedef __bf16 bf16x4 __attribute__((ext_vector_type(4)));
typedef float f32x16 __attribute__((ext_vector_type(16)));
typedef unsigned int uint2v __attribute__((ext_vector_type(2)));

#define MFMA32(a, b, c) __builtin_amdgcn_mfma_f32_32x32x16_bf16(a, b, c, 0, 0, 0)

__device__ __forceinline__ unsigned short f2bf(float f) {
  unsigned int u = __builtin_bit_cast(unsigned int, f);
  u += 0x7fffu + ((u >> 16) & 1u);
  return (unsigned short)(u >> 16);
}

__device__ __forceinline__ unsigned pk2(float a, float b) {
  return (unsigned)f2bf(a) | ((unsigned)f2bf(b) << 16);
}

// ws layout (bf16 elements):
//   [0,65536)        W2 fragments: ((ot*16+ks)*64+lane)*8+j ; o=ot*32+(lane&31), k=ks*16+(lane>>5)*8+j
//   [65536,131072)   W4 fragments, same permutation
//   [131072,135168)  W1-extra frags: lanes<32: j<4 -> W1[o][j], j==4 -> b1[o]+b2[o], else 0
//   [135168,139264)  W3-extra frags: j==4 -> b3[o]+2*b4[o]
// R17: one thread produces 8 consecutive ws elements (one int4 store);
// W rows loaded as 2x float4 (32B aligned since kbase%8==0).
__global__ void prep_kernel(const float* __restrict__ W1, const float* __restrict__ b1,
                            const float* __restrict__ W2, const float* __restrict__ b2,
                            const float* __restrict__ W3, const float* __restrict__ b3,
                            const float* __restrict__ W4, const float* __restrict__ b4,
                            unsigned short* __restrict__ ws) {
  int t8 = blockIdx.x * 256 + threadIdx.x;
  if (t8 >= 17408) return;   // 139264 / 8
  int idx = t8 * 8;
  int4 outv;
  if (idx < 131072) {
    const float* W = (idx < 65536) ? W2 : W4;
    int f = (idx & 65535) >> 3;
    int lane = f & 63, slot = f >> 6;
    int ks = slot & 15, ot = slot >> 4;
    int o = ot * 32 + (lane & 31);
    int kbase = ks * 16 + (lane >> 5) * 8;
    const float4* row = (const float4*)(W + o * 256 + kbase);
    float4 v0 = row[0];
    float4 v1 = row[1];
    outv = make_int4((int)pk2(v0.x, v0.y), (int)pk2(v0.z, v0.w),
                     (int)pk2(v1.x, v1.y), (int)pk2(v1.z, v1.w));
  } else {
    int i = idx - 131072;
    bool first = (i < 4096);
    int f = (i & 4095) >> 3;
    int lane = f & 63, ot = f >> 6;
    int o = ot * 32 + (lane & 31);
    outv = make_int4(0, 0, 0, 0);
    if (lane < 32) {
      const float4 wrow = *(const float4*)((first ? W1 : W3) + o * 4);
      float bias = first ? (b1[o] + b2[o]) : (b3[o] + 2.0f * b4[o]);
      outv = make_int4((int)pk2(wrow.x, wrow.y), (int)pk2(wrow.z, wrow.w),
                       (int)pk2(bias, 0.0f), 0);
    }
  }
  *(int4*)(ws + idx) = outv;
}

#define NC 10  // W2 slots cached (0..3 = self ks); slots 10..15 streamed per GEMM

// Load 2 afs slots (physical ks rotated by 4w) into AF[0..1][ot].
#define LOAD_AF(AF, S0) { \
    int ka_ = (4 * w + NC + (S0)) & 15; \
    AF[0][0] = __builtin_bit_cast(bf16x8, w2f[(ot0 * 16 + ka_) * 64 + l]); \
    AF[0][1] = __builtin_bit_cast(bf16x8, w2f[((ot0 + 1) * 16 + ka_) * 64 + l]); \
    int kb_ = (4 * w + NC + (S0) + 1) & 15; \
    AF[1][0] = __builtin_bit_cast(bf16x8, w2f[(ot0 * 16 + kb_) * 64 + l]); \
    AF[1][1] = __builtin_bit_cast(bf16x8, w2f[((ot0 + 1) * 16 + kb_) * 64 + l]); }

// One LDS-sourced K-slice: 1 ds_read_b128 feeds 2 MFMAs. KSR runtime (addr only).
#define GSTEP(RB, KSR, A0, A1) { \
    bf16x8 bu_ = __builtin_bit_cast(bf16x8, (RB)[(2 * (KSR) + khalf) * 32 + lane31]); \
    acc[0] = MFMA32(A0, bu_, acc[0]); \
    acc[1] = MFMA32(A1, bu_, acc[1]); }

// Self K-slice from zk registers (zero LDS dependency). S literal 0..3.
#define SELFSTEP(ZK, S) { \
    bf16x8 bu_ = __builtin_bit_cast(bf16x8, ZK[(S) >> 1][(S) & 1]); \
    acc[0] = MFMA32(w2c[0][S], bu_, acc[0]); \
    acc[1] = MFMA32(w2c[1][S], bu_, acc[1]); }

// relu + bf16 pack + permlane32_swap into full-int4 B-frag form -> ZK regs.
// ZK[t2][p] = chunk (ot0+t2)*4 + 2p + khalf, row lane31.
#define PACKZ(ZK) { \
    _Pragma("unroll") for (int t2 = 0; t2 < 2; ++t2) { \
      unsigned lo[4], hi[4]; \
      _Pragma("unroll") for (int q = 0; q < 4; ++q) { \
        bf16x4 h; \
        h.x = (__bf16)fmaxf(acc[t2][4 * q + 0], 0.0f); \
        h.y = (__bf16)fmaxf(acc[t2][4 * q + 1], 0.0f); \
        h.z = (__bf16)fmaxf(acc[t2][4 * q + 2], 0.0f); \
        h.w = (__bf16)fmaxf(acc[t2][4 * q + 3], 0.0f); \
        uint2 u = __builtin_bit_cast(uint2, h); \
        lo[q] = u.x; hi[q] = u.y; \
      } \
      uint2v r0 = __builtin_amdgcn_permlane32_swap(lo[0], lo[1], false, false); \
      uint2v r1 = __builtin_amdgcn_permlane32_swap(hi[0], hi[1], false, false); \
      ZK[t2][0] = make_int4((int)r0.x, (int)r1.x, (int)r0.y, (int)r1.y); \
      uint2v r2 = __builtin_amdgcn_permlane32_swap(lo[2], lo[3], false, false); \
      uint2v r3 = __builtin_amdgcn_permlane32_swap(hi[2], hi[3], false, false); \
      ZK[t2][1] = make_int4((int)r2.x, (int)r3.x, (int)r2.y, (int)r3.y); \
    } }

// Write ZK regs (4 int4) into state buffer WB. Conflict-free 512B runs.
#define WRITEZ(ZK, WB) { \
    _Pragma("unroll") for (int t2 = 0; t2 < 2; ++t2) \
    _Pragma("unroll") for (int p = 0; p < 2; ++p) \
      (WB)[((ot0 + t2) * 4 + 2 * p + khalf) * 32 + lane31] = ZK[t2][p]; }

// xw extra-K term for phase PH at step T.
#define XWSTEP(PH, T) { \
    int widx_ = (PH) == 0 ? (lane31 + (T) - 1) : (lane31 + 17 - (T)); \
    const int4* p_ = (l < 32) ? (xw + widx_) : (&zc); \
    bf16x8 bx_ = __builtin_bit_cast(bf16x8, *p_); \
    acc[0] = MFMA32(w1x[0], bx_, acc[0]); \
    acc[1] = MFMA32(w1x[1], bx_, acc[1]); }

// Full DP interval with GEMM: self ks 0..3 from ZK (state T-1), ks 4..15
// cached/streamed, then ZK := state T (packed) and written to WB.
#define INTERVAL_G(PH, T, RB, WB, ZK) { \
  bf16x8 afA[2][2], afB[2][2], afC[2][2]; \
  LOAD_AF(afA, 0) \
  f32x16 acc[2] = {}; \
  XWSTEP(PH, T) \
  __builtin_amdgcn_s_setprio(1); \
  SELFSTEP(ZK, 0) SELFSTEP(ZK, 1) SELFSTEP(ZK, 2) SELFSTEP(ZK, 3) \
  LOAD_AF(afB, 2) \
  GSTEP(RB, (4 * w + 4) & 15, w2c[0][4], w2c[1][4]) \
  GSTEP(RB, (4 * w + 5) & 15, w2c[0][5], w2c[1][5]) \
  GSTEP(RB, (4 * w + 6) & 15, w2c[0][6], w2c[1][6]) \
  GSTEP(RB, (4 * w + 7) & 15, w2c[0][7], w2c[1][7]) \
  GSTEP(RB, (4 * w + 8) & 15, w2c[0][8], w2c[1][8]) \
  GSTEP(RB, (4 * w + 9) & 15, w2c[0][9], w2c[1][9]) \
  GSTEP(RB, (4 * w + 10) & 15, afA[0][0], afA[0][1]) \
  GSTEP(RB, (4 * w + 11) & 15, afA[1][0], afA[1][1]) \
  LOAD_AF(afC, 4) \
  GSTEP(RB, (4 * w + 12) & 15, afB[0][0], afB[0][1]) \
  GSTEP(RB, (4 * w + 13) & 15, afB[1][0], afB[1][1]) \
  GSTEP(RB, (4 * w + 14) & 15, afC[0][0], afC[0][1]) \
  GSTEP(RB, (4 * w + 15) & 15, afC[1][0], afC[1][1]) \
  __builtin_amdgcn_s_setprio(0); \
  PACKZ(ZK) \
  WRITEZ(ZK, WB) }

// Peel interval (T=1): no GEMM.
#define INTERVAL_P(PH, WB, ZK) { \
  f32x16 acc[2] = {}; \
  XWSTEP(PH, 1) \
  PACKZ(ZK) \
  WRITEZ(ZK, WB) }

__global__ __launch_bounds__(256, 2)
void chain_kernel(const float* __restrict__ x, const unsigned short* __restrict__ ws,
                  float* __restrict__ out) {
  // Per-phase double-buffered state, chunk-major: buf[c*32 + r] = bf16 elems
  // [8c..8c+7] of state row r (32 rows per tile). 4 x 16KB = 64KB.
  __shared__ int4 UA[2][1024];
  __shared__ int4 UB[2][1024];
  __shared__ int4 xw[48];   // [x0,x1,x2,x3,1,0,0,0] bf16 chunks, rows j0-8 .. j0+39
  __shared__ int4 zc;

  const int tid = threadIdx.x;
  const int l = tid & 63;
  const int w = tid >> 6;
  const int lane31 = l & 31;
  const int khalf = l >> 5;
  const int tile = blockIdx.x;
  const int b = tile >> 6;
  const int j0 = (tile & 63) * 32;

  const int4* w2f = (const int4*)ws;
  const int4* w4f = (const int4*)(ws + 65536);
  const int4* w1xg = (const int4*)(ws + 131072);
  const int4* w3xg = (const int4*)(ws + 135168);

  if (tid == 0) zc = make_int4(0, 0, 0, 0);
  if (tid < 48) {
    int j = j0 - 8 + tid;
    int4 c = make_int4(0, 0, 0, 0);
    if (j >= 0 && j < 2048) {
      const float* xb = x + (b * 4) * 2048 + j;
      unsigned short h0 = f2bf(xb[0]);
      unsigned short h1 = f2bf(xb[2048]);
      unsigned short h2 = f2bf(xb[4096]);
      unsigned short h3 = f2bf(xb[6144]);
      c = make_int4((int)(h0 | ((unsigned int)h1 << 16)),
                    (int)(h2 | ((unsigned int)h3 << 16)),
                    0x00003f80, 0);  // chunk[4] = bf16(1.0) multiplies the bias row
    }
    xw[tid] = c;
  }

  const int ot0 = w * 2;
  // Rotated W2 cache: slot i = physical ks (4w+i)&15; slots 0..3 are this
  // wave's SELF ks (matching its own zk chunks) at compile-time indices.
  bf16x8 w2c[2][NC];
  bf16x8 w1x[2];
#pragma unroll
  for (int t2 = 0; t2 < 2; ++t2) {
    w1x[t2] = __builtin_bit_cast(bf16x8, w1xg[(ot0 + t2) * 64 + l]);
#pragma unroll
    for (int i = 0; i < NC; ++i) {
      int ksr = (4 * w + i) & 15;
      w2c[t2][i] = __builtin_bit_cast(bf16x8, w2f[((ot0 + t2) * 16 + ksr) * 64 + l]);
    }
  }
  __syncthreads();

  // zkU/zkD: this wave's packed state (B-frag layout), ks slots [4w,4w+4).
  // Lifetime: packed at pair k, LDS-written same pair, self-consumed pair k+1.
  int4 zkU[2][2], zkD[2][2];

  // ---- pair 0 (T=1): no previous state ----
  INTERVAL_P(0, UA[0], zkU)
  INTERVAL_P(1, UB[0], zkD)
  __syncthreads();

  // ---- pairs 1..7 (T=2..8): one barrier per pair ----
#pragma unroll 1
  for (int k = 1; k < 8; ++k) {
    const int4* ra = UA[(k - 1) & 1];
    int4* wa = UA[k & 1];
    const int4* rb = UB[(k - 1) & 1];
    int4* wb = UB[k & 1];
    const int T = k + 1;
    INTERVAL_G(0, T, ra, wa, zkU)
    INTERVAL_G(1, T, rb, wb, zkD)
    __syncthreads();
  }

  // ---- final: miu^T = relu(W3x + b3 + 2b4 + W4*up(8) + W4*down(8)) ----
  // up(8) in UA[1] + zkU self slots; down(8) in UB[1] + zkD.
  {
    f32x16 acc[2] = {};
    { int widx = lane31 + 8;
      const int4* p_ = (l < 32) ? (xw + widx) : (&zc);
      bf16x8 bx = __builtin_bit_cast(bf16x8, *p_);
      bf16x8 w3x0 = __builtin_bit_cast(bf16x8, w3xg[ot0 * 64 + l]);
      bf16x8 w3x1 = __builtin_bit_cast(bf16x8, w3xg[(ot0 + 1) * 64 + l]);
      acc[0] = MFMA32(w3x0, bx, acc[0]);
      acc[1] = MFMA32(w3x1, bx, acc[1]); }
    __builtin_amdgcn_s_setprio(1);
#pragma unroll 1
    for (int ph = 0; ph < 2; ++ph) {
      const int4* Sp = ph ? UB[1] : UA[1];
      const int4* zz = ph ? &zkD[0][0] : &zkU[0][0];
#pragma unroll
      for (int s = 0; s < 4; ++s) {
        int ksr = 4 * w + s;
        bf16x8 af0 = __builtin_bit_cast(bf16x8, w4f[(ot0 * 16 + ksr) * 64 + l]);
        bf16x8 af1 = __builtin_bit_cast(bf16x8, w4f[((ot0 + 1) * 16 + ksr) * 64 + l]);
        bf16x8 bu = __builtin_bit_cast(bf16x8, zz[s]);
        acc[0] = MFMA32(af0, bu, acc[0]);
        acc[1] = MFMA32(af1, bu, acc[1]);
      }
#pragma unroll
      for (int i = 4; i < 16; ++i) {
        int ksr = (4 * w + i) & 15;
        bf16x8 af0 = __builtin_bit_cast(bf16x8, w4f[(ot0 * 16 + ksr) * 64 + l]);
        bf16x8 af1 = __builtin_bit_cast(bf16x8, w4f[((ot0 + 1) * 16 + ksr) * 64 + l]);
        bf16x8 bu = __builtin_bit_cast(bf16x8, Sp[(2 * ksr + khalf) * 32 + lane31]);
        acc[0] = MFMA32(af0, bu, acc[0]);
        acc[1] = MFMA32(af1, bu, acc[1]);
      }
    }
    __builtin_amdgcn_s_setprio(0);
    int pbase = (b * 2048 + j0 + lane31) * 256;
#pragma unroll
    for (int t2 = 0; t2 < 2; ++t2) {
#pragma unroll
      for (int q = 0; q < 4; ++q) {
        int ob = (ot0 + t2) * 32 + 8 * q + 4 * khalf;
        float4 v;
        v.x = fmaxf(acc[t2][4 * q + 0], 0.0f);
        v.y = fmaxf(acc[t2][4 * q + 1], 0.0f);
        v.z = fmaxf(acc[t2][4 * q + 2], 0.0f);
        v.w = fmaxf(acc[t2][4 * q + 3], 0.0f);
        *(float4*)(out + pbase + ob) = v;
      }
    }
  }
}

extern "C" void kernel_launch(void* const* d_in, const int* in_sizes, int n_in,
                              void* d_out, int out_size, void* d_ws, size_t ws_size,
                              hipStream_t stream) {
  const float* x  = (const float*)d_in[0];
  const float* W1 = (const float*)d_in[1];
  const float* b1 = (const float*)d_in[2];
  const float* W2 = (const float*)d_in[3];
  const float* b2 = (const float*)d_in[4];
  const float* W3 = (const float*)d_in[5];
  const float* b3 = (const float*)d_in[6];
  const float* W4 = (const float*)d_in[7];
  const float* b4 = (const float*)d_in[8];
  unsigned short* ws = (unsigned short*)d_ws;

  prep_kernel<<<68, 256, 0, stream>>>(W1, b1, W2, b2, W3, b3, W4, b4, ws);
  chain_kernel<<<1024, 256, 0, stream>>>(x, ws, (float*)d_out);
}